// Round 3
// baseline (115.644 us; speedup 1.0000x reference)
//
#include <hip/hip_runtime.h>
#include <hip/hip_fp16.h>
#include <math.h>

// CTC loss forward, SINGLE fused kernel v5: pipelined producer-consumer
// (v3/v4) + PREFETCH DEPTH 2 in the producers.
// One block of 1024 threads (16 waves) per batch element; B=256 = 256 CUs.
//
// v4 lesson: straight-lining the round body was NULL -> prep is not
// issue/ILP-bound. Arithmetic bounds: VALU ~5 us, HBM floor ~10.6 us,
// LDS ~4 us, measured prep ~26 us -> latency-stalled, not saturated.
// Remaining theory: MLP. Depth-1 prefetch = only 4 outstanding 1KB loads
// per wave, issued spread over a ~600cy round; under full-chip queuing the
// slack (~1 round) < effective latency -> serial load-wait-compute.
// v5: depth-2 ping-pong prefetch (named va/vbb buffers, static indexing per
// rule #20): 8 loads in flight per wave, slack = 2 rounds, 120 KB/CU burst
// at t=0. Chain math identical (absmax = 1 bf16 ulp).
// B=256, T=512, C=128 (blank=127), L=64, S=129.

constexpr int Cc = 128;
constexpr int Tt = 512;
constexpr int Ll = 64;
constexpr int NCH = Tt / 8;                 // 64 chunks of 8 timesteps
constexpr int NPW = 15;                     // producer waves (wave 1..15)
constexpr int NR  = (NCH + NPW - 1) / NPW;  // 5 rounds
constexpr float INV_LN2 = 1.4426950408889634f;
constexpr float LN2_F   = 0.6931471805599453f;

__device__ __forceinline__ float fexp2(float x) { return __builtin_amdgcn_exp2f(x); }
__device__ __forceinline__ float flog2(float x) { return __builtin_amdgcn_logf(x); }

template<int CTRL, bool BC>
__device__ __forceinline__ float dppf(float old, float x) {
    return __int_as_float(__builtin_amdgcn_update_dpp(
        __float_as_int(old), __float_as_int(x), CTRL, 0xF, 0xF, BC));
}
// lane i <- lane i-1 across whole wave; lane 0 <- fill. (silicon-proven r3-r7)
__device__ __forceinline__ float wshr1(float x, float fill) { return dppf<0x138, false>(fill, x); }

__device__ __forceinline__ float rlf(float v, int lane) {
    return __int_as_float(__builtin_amdgcn_readlane(__float_as_int(v), lane));
}
// Row-local (16-lane) reduce; lanes 15/31/47/63 hold row results. (proven r6/r7)
__device__ __forceinline__ float rowsum(float e) {
    e += dppf<0x111, true>(0.f, e);
    e += dppf<0x112, true>(0.f, e);
    e += dppf<0x114, true>(0.f, e);
    e += dppf<0x118, true>(0.f, e);
    return e;
}
__device__ __forceinline__ float rowmax(float m) {   // m >= 0 (0-fill identity)
    m = fmaxf(m, dppf<0x111, true>(0.f, m));
    m = fmaxf(m, dppf<0x112, true>(0.f, m));
    m = fmaxf(m, dppf<0x114, true>(0.f, m));
    m = fmaxf(m, dppf<0x118, true>(0.f, m));
    return m;
}
__device__ __forceinline__ float allmax(float m) {
    m = rowmax(m);
    return fmaxf(fmaxf(rlf(m, 15), rlf(m, 31)), fmaxf(rlf(m, 47), rlf(m, 63)));
}
__device__ __forceinline__ float bperm_f(int srclane, float v) {
    return __int_as_float(__builtin_amdgcn_ds_bpermute(srclane << 2, __float_as_int(v)));
}
__device__ __forceinline__ float gather4(float4 v, int srclane, int csel) {
    const float gx = bperm_f(srclane, v.x), gy = bperm_f(srclane, v.y);
    const float gz = bperm_f(srclane, v.z), gw = bperm_f(srclane, v.w);
    const float lo = (csel & 1) ? gy : gx;
    const float hi = (csel & 1) ? gw : gz;
    return (csel & 2) ? hi : lo;
}

// 8 chain steps + zero-lag renorm on a packed fp16 chunk (proven r7; v3:
// re-associated so the serial path is DPP -> fma -> fma).
template<bool GUARD>
__device__ __forceinline__ void do_chunk(uint4 raw, int t0, int inlen, float skf,
                                         float& aO, float& aE, float& r0, float& Rtot)
{
    float dv[8];
    {
        const __half2 h0 = *reinterpret_cast<const __half2*>(&raw.x);
        const __half2 h1 = *reinterpret_cast<const __half2*>(&raw.y);
        const __half2 h2 = *reinterpret_cast<const __half2*>(&raw.z);
        const __half2 h3 = *reinterpret_cast<const __half2*>(&raw.w);
        dv[0] = __low2float(h0); dv[1] = __high2float(h0);
        dv[2] = __low2float(h1); dv[3] = __high2float(h1);
        dv[4] = __low2float(h2); dv[5] = __high2float(h2);
        dv[6] = __low2float(h3); dv[7] = __high2float(h3);
    }
    float sd[8];
#pragma unroll
    for (int j = 0; j < 8; ++j) sd[j] = skf * dv[j];   // off critical path
#pragma unroll
    for (int j = 0; j < 8; ++j) {
        if (!GUARD || (t0 + j < inlen)) {
            const float ad = aO * dv[j];        // starts as soon as aO settles
            const float pE = wshr1(aE, r0);     // beta[2l]; lane0: state0
            const float pO = wshr1(aO, 0.0f);   // beta[2l-1]
            const float nO = fmaf(pE, dv[j], fmaf(pO, sd[j], ad));
            aE += aO;
            aO = nO;
        }
    }
    const float M_ = allmax(fmaxf(fmaxf(aO, aE), r0));
    int R_ = (int)(__float_as_uint(M_) >> 23) - 127;
    R_ = (R_ < 0) ? 0 : ((R_ > 126) ? 126 : R_);
    const float sc = __uint_as_float((unsigned)(127 - R_) << 23);
    aO = fminf(aO * sc, 4.0f);
    aE = fminf(aE * sc, 4.0f);
    r0 = fminf(r0 * sc, 4.0f);
    Rtot += (float)R_;
}

__global__ __launch_bounds__(1024, 1) void ctc_fused5_kernel(
    const int* __restrict__ y_true,      // [B, 64]
    const float* __restrict__ y_pred,    // [B, T, C]
    const int* __restrict__ in_len,      // [B]
    const int* __restrict__ lab_len,     // [B]
    float* __restrict__ out)             // [B]
{
    __shared__ __half w_lds[NCH][64][8];  // [chunk][lane][t&7], 64 KB
    __shared__ float  ps[NPW];            // per-producer-wave blank partial sums (log2)
    __shared__ int    rctr[NR];           // per-round completion counters

    const int b   = blockIdx.x;
    const int tid = threadIdx.x;
    const int w   = tid >> 6;             // wave 0..15
    const int l   = tid & 63;

    if (tid < NR) rctr[tid] = 0;
    __syncthreads();

    int inlen = in_len[b]; if (inlen < 1) inlen = 1; if (inlen > Tt) inlen = Tt;
    int LLv   = lab_len[b]; if (LLv < 1) LLv = 1; if (LLv > Ll) LLv = Ll;

    const int lab = y_true[b * Ll + l] & 127;
    const float* rowbase = y_pred + (size_t)b * Tt * Cc;

    if (w != 0) {
        // ---------------- producers: waves 1..15, round-robin chunk order -------
        // Depth-2 ping-pong prefetch: va = round r data, vbb = round r+1 data.
        const int pw   = w - 1;
        const int half = l >> 5, li = l & 31;
        const int srcA = lab >> 2;        // lane (in low half) holding class `lab`
        const int csel = lab & 3;
        const bool live = (l < LLv);      // r6 fix: dead lattice lanes -> w = 0

        float acc = 0.0f;                 // sum of lp2_blank over rows < inlen

        float4 va[4], vbb[4];
#pragma unroll
        for (int j = 0; j < 4; ++j) {     // preload rounds 0 and 1 (both in-bounds:
            va[j]  = ((const float4*)(rowbase + (size_t)((pw      ) * 8 + 2 * j + half) * Cc))[li];
            vbb[j] = ((const float4*)(rowbase + (size_t)((pw + NPW) * 8 + 2 * j + half) * Cc))[li];
        }                                 //  pw+NPW <= 29 < NCH always)

        // one producer round: consume buf (round r's data), prefetch round r+2
        // into buf. cpre clamped -> loads always legal, body one basic block.
        auto process = [&](int c, int r, float4 (&buf)[4]) {
            const int cf = c + 2 * NPW;
            const int cpre = (cf < NCH) ? cf : (NCH - 1);
            float prod = 1.0f, bsum = 0.0f;
#pragma unroll
            for (int j = 0; j < 4; ++j) {
                const float4 v = buf[j];
                buf[j] = ((const float4*)(rowbase + (size_t)(cpre * 8 + 2 * j + half) * Cc))[li];

                const int rA = c * 8 + 2 * j;
                const int rB = rA + 1;

                // row-pair softmax denominators (log2 deferred to round tail)
                float e = (fexp2(v.x * INV_LN2) + fexp2(v.y * INV_LN2))
                        + (fexp2(v.z * INV_LN2) + fexp2(v.w * INV_LN2));
                e = rowsum(e);
                const float sA = rlf(e, 15) + rlf(e, 31);
                const float sB = rlf(e, 47) + rlf(e, 63);
                const float blA = rlf(v.w, 31);      // blank logit, row A (uniform)
                const float blB = rlf(v.w, 63);      // blank logit, row B

                const bool okA = rA < inlen, okB = rB < inlen;
                prod *= okB ? sA * sB : (okA ? sA : 1.0f);   // dead rows -> 1
                bsum += okB ? blA + blB : (okA ? blA : 0.0f);

                // per-lane label weights -> LDS chunk layout
                const float xA = gather4(v, srcA, csel);
                const float xB = gather4(v, srcA + 32, csel);
                float wA = fminf(fmaxf(fexp2((xA - blA) * INV_LN2), 6.1e-5f), 8192.0f);
                float wB = fminf(fmaxf(fexp2((xB - blB) * INV_LN2), 6.1e-5f), 8192.0f);
                wA = live ? wA : 0.0f;
                wB = live ? wB : 0.0f;
                const unsigned packed =
                      (unsigned)__half_as_ushort(__float2half(wA))
                    | ((unsigned)__half_as_ushort(__float2half(wB)) << 16);
                *(unsigned*)&w_lds[c][l][2 * j] = packed;   // 2j even: 4B aligned
            }
            // fold: acc += bsum*INV_LN2 - sum(log2 s) via single log2 of product
            acc = fmaf(bsum, INV_LN2, acc) - flog2(prod);
            // last chunk for this wave: publish blank partial BEFORE the flag
            if (c + NPW >= NCH && l == 0) ps[pw] = acc;
            // drain this wave's ds_writes, then bump the round counter
            asm volatile("s_waitcnt lgkmcnt(0)" ::: "memory");
            if (l == 0) atomicAdd(&rctr[r], 1);
        };

        int c = pw, r = 0;
        while (true) {
            process(c, r, va);            // even round -> va
            c += NPW; ++r;
            if (c >= NCH) break;
            process(c, r, vbb);           // odd round -> vbb
            c += NPW; ++r;
            if (c >= NCH) break;
        }
        return;   // producers never wait on the consumer -> no deadlock
    }

    // ---------------- consumer: wave 0, 512-step linear recurrence -------------
    const int labp = __shfl_up(lab, 1, 64);
    const float skf = ((l >= 1) && (lab != labp)) ? 1.0f : 0.0f;

    float aO = 0.0f, aE = 0.0f, r0 = 1.0f, Rtot = 0.0f;
    const int nchunks = (inlen + 7) >> 3;       // >= 32

    volatile int* vctr = rctr;
    int ready = 0, rr = 0;
    // ensure chunks 0..cneed are published (fast path: scalar compare only)
    auto wait_upto = [&](int cneed) {
        while (ready <= cneed) {
            const int rem  = NCH - rr * NPW;
            const int need = rem < NPW ? rem : NPW;
            if (vctr[rr] >= need) { ready += need; ++rr; }
            else __builtin_amdgcn_s_sleep(1);
        }
        asm volatile("" ::: "memory");          // acquire: no hoisting of data reads
    };

    wait_upto(0);
    uint4 A = *(const uint4*)&w_lds[0][l][0];
    for (int c = 0; c < nchunks; ++c) {
        uint4 Bv = A;
        if (c + 1 < nchunks) {                  // prefetch next chunk once ready
            wait_upto(c + 1);
            Bv = *(const uint4*)&w_lds[c + 1][l][0];
        }
        const int t0 = c * 8;
        if (t0 + 8 <= inlen) do_chunk<false>(A, t0, inlen, skf, aO, aE, r0, Rtot);
        else                 do_chunk<true >(A, t0, inlen, skf, aO, aE, r0, Rtot);
        A = Bv;
    }

    // wait for ALL rounds (every producer past its final flag => ps[] complete)
    while (rr < NR) {
        const int rem  = NCH - rr * NPW;
        const int need = rem < NPW ? rem : NPW;
        if (vctr[rr] >= need) ++rr;
        else __builtin_amdgcn_s_sleep(1);
    }
    asm volatile("" ::: "memory");

    // cum_blank (log2): sum the 15 per-wave partials (uniform)
    float cum_b = 0.0f;
#pragma unroll
    for (int q = 0; q < NPW; ++q) cum_b += ps[q];

    // readout: states 2*LL (aE) and 2*LL-1 (aO) live on lane LL-1
    const float aEr = __shfl(aE, LLv - 1, 64);
    const float aOr = __shfl(aO, LLv - 1, 64);
    if (l == 0)
        out[b] = -LN2_F * (flog2(fmaxf(aEr + aOr, 1e-37f)) + Rtot + cum_b);
}

extern "C" void kernel_launch(void* const* d_in, const int* in_sizes, int n_in,
                              void* d_out, int out_size, void* d_ws, size_t ws_size,
                              hipStream_t stream) {
    const int*   y_true  = (const int*)d_in[0];    // [256,64]
    const float* y_pred  = (const float*)d_in[1];  // [256,512,128]
    const int*   in_len  = (const int*)d_in[2];    // [256]
    const int*   lab_len = (const int*)d_in[3];    // [256]
    float*       out     = (float*)d_out;          // [256]
    (void)d_ws; (void)ws_size;

    ctc_fused5_kernel<<<256, 1024, 0, stream>>>(y_true, y_pred, in_len, lab_len, out);
}

// Round 5
// 109.655 us; speedup vs baseline: 1.0546x; 1.0546x over previous
//
#include <hip/hip_runtime.h>
#include <hip/hip_fp16.h>
#include <math.h>

// CTC loss forward, SINGLE fused kernel v7: forward-backward split chain
// (v6) + EXPONENT-SAFE meeting-point dot.
// One block of 1024 threads (16 waves) per batch element; B=256 = 256 CUs.
//
// v6 FAILED with absmax 80 = ln2*115: the meeting dot s = sum_l a_l*b_l
// underflowed f32 (each half renormalized to max~1, but per-lane products
// ~2^-120 flush to denormal/zero; fmaxf(s,1e-37)=2^-123 clamps; true
// s ~ 2^-238 -> error ln2*(238-123) = 80 EXACTLY). Lattice algebra
// (transpose step, guards, split counters) verified symbolically - only the
// combiner was unsafe. v7: per-lane contributions in DOUBLE (f32*f32 ->
// f64 cannot underflow), 64-lane butterfly reduce via paired 32-bit
// shuffles, log2 via exponent extraction + flog2(mantissa). One-time cost.
// B=256, T=512, C=128 (blank=127), L=64, S=129.

constexpr int Cc = 128;
constexpr int Tt = 512;
constexpr int Ll = 64;
constexpr int NPS = 7;                      // producer waves per side
constexpr float INV_LN2 = 1.4426950408889634f;
constexpr float LN2_F   = 0.6931471805599453f;

__device__ __forceinline__ float fexp2(float x) { return __builtin_amdgcn_exp2f(x); }
__device__ __forceinline__ float flog2(float x) { return __builtin_amdgcn_logf(x); }

template<int CTRL, bool BC>
__device__ __forceinline__ float dppf(float old, float x) {
    return __int_as_float(__builtin_amdgcn_update_dpp(
        __float_as_int(old), __float_as_int(x), CTRL, 0xF, 0xF, BC));
}
// lane i <- lane i-1; lane 0 <- fill. (silicon-proven r3-r7)
__device__ __forceinline__ float wshr1(float x, float fill) { return dppf<0x138, false>(fill, x); }
// lane i <- lane i+1; lane 63 <- fill. (wave_shl1, mirror of 0x138)
__device__ __forceinline__ float wshl1(float x, float fill) { return dppf<0x130, false>(fill, x); }

__device__ __forceinline__ float rlf(float v, int lane) {
    return __int_as_float(__builtin_amdgcn_readlane(__float_as_int(v), lane));
}
// Row-local (16-lane) reduce; lanes 15/31/47/63 hold row results. (proven r6/r7)
__device__ __forceinline__ float rowsum(float e) {
    e += dppf<0x111, true>(0.f, e);
    e += dppf<0x112, true>(0.f, e);
    e += dppf<0x114, true>(0.f, e);
    e += dppf<0x118, true>(0.f, e);
    return e;
}
__device__ __forceinline__ float rowmax(float m) {   // m >= 0 (0-fill identity)
    m = fmaxf(m, dppf<0x111, true>(0.f, m));
    m = fmaxf(m, dppf<0x112, true>(0.f, m));
    m = fmaxf(m, dppf<0x114, true>(0.f, m));
    m = fmaxf(m, dppf<0x118, true>(0.f, m));
    return m;
}
__device__ __forceinline__ float allmax(float m) {
    m = rowmax(m);
    return fmaxf(fmaxf(rlf(m, 15), rlf(m, 31)), fmaxf(rlf(m, 47), rlf(m, 63)));
}
__device__ __forceinline__ float bperm_f(int srclane, float v) {
    return __int_as_float(__builtin_amdgcn_ds_bpermute(srclane << 2, __float_as_int(v)));
}
__device__ __forceinline__ float gather4(float4 v, int srclane, int csel) {
    const float gx = bperm_f(srclane, v.x), gy = bperm_f(srclane, v.y);
    const float gz = bperm_f(srclane, v.z), gw = bperm_f(srclane, v.w);
    const float lo = (csel & 1) ? gy : gx;
    const float hi = (csel & 1) ? gw : gz;
    return (csel & 2) ? hi : lo;
}
// double butterfly-xor shuffle (two 32-bit halves)
__device__ __forceinline__ double shflx_d(double v, int mask) {
    const long long x = __double_as_longlong(v);
    int lo = (int)(x & 0xffffffffLL), hi = (int)(x >> 32);
    lo = __shfl_xor(lo, mask, 64);
    hi = __shfl_xor(hi, mask, 64);
    return __longlong_as_double(((long long)hi << 32) | (unsigned)(unsigned int)lo);
}

__device__ __forceinline__ void unpack8(uint4 raw, float (&dv)[8]) {
    const __half2 h0 = *reinterpret_cast<const __half2*>(&raw.x);
    const __half2 h1 = *reinterpret_cast<const __half2*>(&raw.y);
    const __half2 h2 = *reinterpret_cast<const __half2*>(&raw.z);
    const __half2 h3 = *reinterpret_cast<const __half2*>(&raw.w);
    dv[0] = __low2float(h0); dv[1] = __high2float(h0);
    dv[2] = __low2float(h1); dv[3] = __high2float(h1);
    dv[4] = __low2float(h2); dv[5] = __high2float(h2);
    dv[6] = __low2float(h3); dv[7] = __high2float(h3);
}

// ---- forward: 8 steps + zero-lag renorm (proven r7/v3) ----
template<bool GUARD>
__device__ __forceinline__ void do_chunk(uint4 raw, int t0, int inlen, float skf,
                                         float& aO, float& aE, float& r0, float& Rtot)
{
    float dv[8]; unpack8(raw, dv);
    float sd[8];
#pragma unroll
    for (int j = 0; j < 8; ++j) sd[j] = skf * dv[j];
#pragma unroll
    for (int j = 0; j < 8; ++j) {
        if (!GUARD || (t0 + j < inlen)) {
            const float ad = aO * dv[j];
            const float pE = wshr1(aE, r0);
            const float pO = wshr1(aO, 0.0f);
            const float nO = fmaf(pE, dv[j], fmaf(pO, sd[j], ad));
            aE += aO;
            aO = nO;
        }
    }
    const float M_ = allmax(fmaxf(fmaxf(aO, aE), r0));
    int R_ = (int)(__float_as_uint(M_) >> 23) - 127;
    R_ = (R_ < 0) ? 0 : ((R_ > 126) ? 126 : R_);
    const float sc = __uint_as_float((unsigned)(127 - R_) << 23);
    aO = fminf(aO * sc, 4.0f);
    aE = fminf(aE * sc, 4.0f);
    r0 = fminf(r0 * sc, 4.0f);
    Rtot += (float)R_;
}

// ---- backward (transpose of the forward step), j descending ----
// bO_l' = w_l*bO_l + bE_l + skf_{l+1}*(w*bO)_{l+1};  bE_l' = bE_l + (w*bO)_{l+1}
// br0'  = br0 + w_0*bO_0   (lane0-valid accumulator; other lanes garbage,
//                           masked at renorm, clamped by fmin 4)
template<bool GUARD>
__device__ __forceinline__ void do_chunk_bwd(uint4 raw, int t0, int inlen, float skfb,
                                             float& bO, float& bE, float& br, float& Rb,
                                             int l)
{
    float dv[8]; unpack8(raw, dv);
#pragma unroll
    for (int j = 7; j >= 0; --j) {
        if (!GUARD || (t0 + j < inlen)) {
            const float BOw = bO * dv[j];
            const float uO  = wshl1(BOw, 0.0f);
            const float t1  = bE + BOw;
            bE += uO;
            br += BOw;
            bO  = fmaf(skfb, uO, t1);
        }
    }
    const float brm = (l == 0) ? br : 0.0f;
    const float M_ = allmax(fmaxf(fmaxf(bO, bE), brm));
    int R_ = (int)(__float_as_uint(M_) >> 23) - 127;
    R_ = (R_ < 0) ? 0 : ((R_ > 126) ? 126 : R_);
    const float sc = __uint_as_float((unsigned)(127 - R_) << 23);
    bO = fminf(bO * sc, 4.0f);
    bE = fminf(bE * sc, 4.0f);
    br = fminf(br * sc, 4.0f);
    Rb += (float)R_;
}

__global__ __launch_bounds__(1024, 1) void ctc_fused7_kernel(
    const int* __restrict__ y_true,      // [B, 64]
    const float* __restrict__ y_pred,    // [B, T, C]
    const int* __restrict__ in_len,      // [B]
    const int* __restrict__ lab_len,     // [B]
    float* __restrict__ out)             // [B]
{
    __shared__ __half w_lds[Tt / 8][64][8];   // [chunk][lane][t&7], 64 KB
    __shared__ float  ps[2 * NPS];            // per-producer blank partials (log2)
    __shared__ int    fctr[5], bctr[5];       // per-round counters (asc / desc)
    __shared__ int    bdone, pdone;
    __shared__ float  bstate[130];            // bE[64], bO[64], br0, Rb

    const int b   = blockIdx.x;
    const int tid = threadIdx.x;
    const int w   = tid >> 6;            // wave 0..15
    const int l   = tid & 63;

    if (tid < 5) { fctr[tid] = 0; bctr[tid] = 0; }
    if (tid == 0) { bdone = 0; pdone = 0; }
    __syncthreads();

    int inlen = in_len[b]; if (inlen < 1) inlen = 1; if (inlen > Tt) inlen = Tt;
    int LLv   = lab_len[b]; if (LLv < 1) LLv = 1; if (LLv > Ll) LLv = Ll;

    const int nct  = (inlen + 7) >> 3;   // total chunks (>= 32)
    const int nchf = nct >> 1;           // forward chunks [0, nchf)
    const int nchb = nct - nchf;         // backward chunks [nchf, nct), top-down

    const int lab = y_true[b * Ll + l] & 127;
    const float* rowbase = y_pred + (size_t)b * Tt * Cc;

    if (w >= 2) {
        // ---------------- producers: 7 ascending (w=2..8), 7 descending ---------
        const bool asc = (w < 9);
        const int pw    = asc ? (w - 2) : (w - 9);
        const int nside = asc ? nchf : nchb;
        const int half = l >> 5, li = l & 31;
        const int srcA = lab >> 2;
        const int csel = lab & 3;
        const bool live = (l < LLv);
        int* ctr = asc ? fctr : bctr;

        float acc = 0.0f;

        if (pw < nside) {
            const int c0 = asc ? pw : (nct - 1 - pw);
            float4 vb[4];
#pragma unroll
            for (int j = 0; j < 4; ++j)
                vb[j] = ((const float4*)(rowbase + (size_t)(c0 * 8 + 2 * j + half) * Cc))[li];

            for (int k = pw, idx = 0; k < nside; k += NPS, ++idx) {
                const int c  = asc ? k : (nct - 1 - k);
                const int kn = k + NPS;
                const int cn = (kn < nside) ? (asc ? kn : (nct - 1 - kn)) : 0;  // clamp: legal dummy
                float prod = 1.0f, bsum = 0.0f;
#pragma unroll
                for (int j = 0; j < 4; ++j) {
                    const float4 v = vb[j];
                    vb[j] = ((const float4*)(rowbase + (size_t)(cn * 8 + 2 * j + half) * Cc))[li];

                    const int rA = c * 8 + 2 * j;
                    const int rB = rA + 1;

                    float e = (fexp2(v.x * INV_LN2) + fexp2(v.y * INV_LN2))
                            + (fexp2(v.z * INV_LN2) + fexp2(v.w * INV_LN2));
                    e = rowsum(e);
                    const float sA = rlf(e, 15) + rlf(e, 31);
                    const float sB = rlf(e, 47) + rlf(e, 63);
                    const float blA = rlf(v.w, 31);
                    const float blB = rlf(v.w, 63);

                    const bool okA = rA < inlen, okB = rB < inlen;
                    prod *= okB ? sA * sB : (okA ? sA : 1.0f);
                    bsum += okB ? blA + blB : (okA ? blA : 0.0f);

                    const float xA = gather4(v, srcA, csel);
                    const float xB = gather4(v, srcA + 32, csel);
                    float wA = fminf(fmaxf(fexp2((xA - blA) * INV_LN2), 6.1e-5f), 8192.0f);
                    float wB = fminf(fmaxf(fexp2((xB - blB) * INV_LN2), 6.1e-5f), 8192.0f);
                    wA = live ? wA : 0.0f;
                    wB = live ? wB : 0.0f;
                    const unsigned packed =
                          (unsigned)__half_as_ushort(__float2half(wA))
                        | ((unsigned)__half_as_ushort(__float2half(wB)) << 16);
                    *(unsigned*)&w_lds[c][l][2 * j] = packed;
                }
                acc = fmaf(bsum, INV_LN2, acc) - flog2(prod);
                asm volatile("s_waitcnt lgkmcnt(0)" ::: "memory");
                if (l == 0) atomicAdd(&ctr[idx], 1);
            }
        }
        if (l == 0) ps[(asc ? 0 : NPS) + pw] = acc;
        asm volatile("s_waitcnt lgkmcnt(0)" ::: "memory");
        if (l == 0) atomicAdd(&pdone, 1);
        return;
    }

    // common to both consumers
    const int labp = __shfl_up(lab, 1, 64);
    const float skf = ((l >= 1) && (lab != labp)) ? 1.0f : 0.0f;

    if (w == 1) {
        // ---------------- backward consumer: beta recurrence, top-down ----------
        const float skfb = __shfl(skf, (l + 1) & 63, 64); // lane63: uO=0, value unused
        float bE = (l == LLv - 1) ? 1.0f : 0.0f;     // state 2*LLv (final blank)
        float bO = bE;                               // state 2*LLv-1 (final label)
        float br = 0.0f, Rb = 0.0f;

        volatile int* vd = bctr;
        int readyd = 0, rrd = 0;
        auto wait_d = [&](int cb) {                  // chunk cb ready (top-down count)
            const int needcnt = nct - cb;
            while (readyd < needcnt) {
                const int rem  = nchb - rrd * NPS;
                const int need = rem < NPS ? rem : NPS;
                if (vd[rrd] >= need) { readyd += need; ++rrd; }
                else __builtin_amdgcn_s_sleep(1);
            }
            asm volatile("" ::: "memory");
        };

        if (nchb > 0) {
            wait_d(nct - 1);
            uint4 A = *(const uint4*)&w_lds[nct - 1][l][0];
            for (int cb = nct - 1; cb >= nchf; --cb) {
                uint4 Bv = A;
                if (cb - 1 >= nchf) { wait_d(cb - 1); Bv = *(const uint4*)&w_lds[cb - 1][l][0]; }
                const int t0 = cb * 8;
                if (t0 + 8 <= inlen) do_chunk_bwd<false>(A, t0, inlen, skfb, bO, bE, br, Rb, l);
                else                 do_chunk_bwd<true >(A, t0, inlen, skfb, bO, bE, br, Rb, l);
                A = Bv;
            }
        }
        bstate[l]      = bE;
        bstate[64 + l] = bO;
        if (l == 0) { bstate[128] = br; bstate[129] = Rb; }
        asm volatile("s_waitcnt lgkmcnt(0)" ::: "memory");
        if (l == 0) atomicExch(&bdone, 1);
        return;
    }

    // ---------------- forward consumer: alpha recurrence, chunks [0,nchf) -------
    float aO = 0.0f, aE = 0.0f, r0 = 1.0f, Rf = 0.0f;

    volatile int* vf = fctr;
    int readyf = 0, rrf = 0;
    auto wait_f = [&](int cneed) {
        while (readyf <= cneed) {
            const int rem  = nchf - rrf * NPS;
            const int need = rem < NPS ? rem : NPS;
            if (vf[rrf] >= need) { readyf += need; ++rrf; }
            else __builtin_amdgcn_s_sleep(1);
        }
        asm volatile("" ::: "memory");
    };

    if (nchf > 0) {
        wait_f(0);
        uint4 A = *(const uint4*)&w_lds[0][l][0];
        for (int c = 0; c < nchf; ++c) {
            uint4 Bv = A;
            if (c + 1 < nchf) { wait_f(c + 1); Bv = *(const uint4*)&w_lds[c + 1][l][0]; }
            const int t0 = c * 8;
            if (t0 + 8 <= inlen) do_chunk<false>(A, t0, inlen, skf, aO, aE, r0, Rf);
            else                 do_chunk<true >(A, t0, inlen, skf, aO, aE, r0, Rf);
            A = Bv;
        }
    }

    // wait: all producers published ps; backward published bstate
    {
        volatile int* vp = &pdone;
        while (*vp < 2 * NPS) __builtin_amdgcn_s_sleep(1);
        volatile int* vbd = &bdone;
        while (*vbd == 0) __builtin_amdgcn_s_sleep(1);
        asm volatile("" ::: "memory");
    }

    float cum_b = 0.0f;
#pragma unroll
    for (int q = 0; q < 2 * NPS; ++q) cum_b += ps[q];

    // meeting-point dot in DOUBLE (exponent-safe): s = sum_s alpha(s)*beta(s)
    const float bEl = bstate[l], bOl = bstate[64 + l];
    const float br0 = bstate[128], Rb = bstate[129];
    double cd = (double)aE * (double)bEl + (double)aO * (double)bOl;
    if (l == 0) cd += (double)r0 * (double)br0;
#pragma unroll
    for (int mk = 1; mk < 64; mk <<= 1) cd += shflx_d(cd, mk);
    // log2 of the double via exponent extraction (cd uniform across lanes now)
    double sd_ = cd > 1e-300 ? cd : 1e-300;
    const long long u = __double_as_longlong(sd_);
    const int e2 = (int)((u >> 52) & 0x7ff) - 1023;
    const double mant = __longlong_as_double((u & 0xfffffffffffffLL) | 0x3ff0000000000000LL);
    const float l2s = (float)e2 + flog2((float)mant);
    if (l == 0)
        out[b] = -LN2_F * (l2s + Rf + Rb + cum_b);
}

extern "C" void kernel_launch(void* const* d_in, const int* in_sizes, int n_in,
                              void* d_out, int out_size, void* d_ws, size_t ws_size,
                              hipStream_t stream) {
    const int*   y_true  = (const int*)d_in[0];    // [256,64]
    const float* y_pred  = (const float*)d_in[1];  // [256,512,128]
    const int*   in_len  = (const int*)d_in[2];    // [256]
    const int*   lab_len = (const int*)d_in[3];    // [256]
    float*       out     = (float*)d_out;          // [256]
    (void)d_ws; (void)ws_size;

    ctc_fused7_kernel<<<256, 1024, 0, stream>>>(y_true, y_pred, in_len, lab_len, out);
}

// Round 6
// 108.972 us; speedup vs baseline: 1.0612x; 1.0063x over previous
//
#include <hip/hip_runtime.h>
#include <hip/hip_fp16.h>
#include <math.h>

// CTC loss forward, SINGLE fused kernel v8: fwd-bwd split (v7) +
// CONDITIONAL RENORM + shfl-based cross-lane (hazard diet).
// One block of 1024 threads (16 waves) per batch element; B=256 = 256 CUs.
//
// v7 lesson: split gave only ~2us. Refit of v5 counters: tail VALU-issue
// ~10-14% -> chain ~85% STALLED, ~2000cy/chunk. Dominant cost is the
// per-chunk exact renorm: DPP rowmax + readlane->SALU->VALU ping-pongs
// (heavy waitstates at 1 wave/SIMD). v8:
//  (a) renorm only when __any(max >= 2^24) (3-op trigger; fires ~1/2-3
//      chunks). Safety: post-renorm max<2, worst real-data chunk growth
//      ~2^51 -> peak 2^75 << 2^127; f64 combiner absorbs the 2^24 scales.
//      Rtot exact (updates only on trigger).
//  (b) triggered renorm's 64-lane max via shfl_xor butterfly (VGPR-only).
//  (c) producers: readlane broadcasts -> __shfl (bpermute), no SALU trips.
// B=256, T=512, C=128 (blank=127), L=64, S=129.

constexpr int Cc = 128;
constexpr int Tt = 512;
constexpr int Ll = 64;
constexpr int NPS = 7;                      // producer waves per side
constexpr float INV_LN2 = 1.4426950408889634f;
constexpr float LN2_F   = 0.6931471805599453f;
constexpr float RENORM_THR = 16777216.0f;   // 2^24

__device__ __forceinline__ float fexp2(float x) { return __builtin_amdgcn_exp2f(x); }
__device__ __forceinline__ float flog2(float x) { return __builtin_amdgcn_logf(x); }

template<int CTRL, bool BC>
__device__ __forceinline__ float dppf(float old, float x) {
    return __int_as_float(__builtin_amdgcn_update_dpp(
        __float_as_int(old), __float_as_int(x), CTRL, 0xF, 0xF, BC));
}
// lane i <- lane i-1; lane 0 <- fill. (silicon-proven r3-r7)
__device__ __forceinline__ float wshr1(float x, float fill) { return dppf<0x138, false>(fill, x); }
// lane i <- lane i+1; lane 63 <- fill. (wave_shl1, mirror, proven v7)
__device__ __forceinline__ float wshl1(float x, float fill) { return dppf<0x130, false>(fill, x); }

// Row-local (16-lane) reduce; lanes 15/31/47/63 hold row results. (proven r6/r7)
__device__ __forceinline__ float rowsum(float e) {
    e += dppf<0x111, true>(0.f, e);
    e += dppf<0x112, true>(0.f, e);
    e += dppf<0x114, true>(0.f, e);
    e += dppf<0x118, true>(0.f, e);
    return e;
}
// all-lane wave max via butterfly shuffles (VGPR-only, no SALU hazards)
__device__ __forceinline__ float xmax64(float m) {
    m = fmaxf(m, __shfl_xor(m, 32, 64));
    m = fmaxf(m, __shfl_xor(m, 16, 64));
    m = fmaxf(m, __shfl_xor(m,  8, 64));
    m = fmaxf(m, __shfl_xor(m,  4, 64));
    m = fmaxf(m, __shfl_xor(m,  2, 64));
    m = fmaxf(m, __shfl_xor(m,  1, 64));
    return m;
}
// all-lane broadcast of a fixed lane (bpermute; stays in VGPRs)
__device__ __forceinline__ float sflf(float v, int lane) { return __shfl(v, lane, 64); }

__device__ __forceinline__ float bperm_f(int srclane, float v) {
    return __int_as_float(__builtin_amdgcn_ds_bpermute(srclane << 2, __float_as_int(v)));
}
__device__ __forceinline__ float gather4(float4 v, int srclane, int csel) {
    const float gx = bperm_f(srclane, v.x), gy = bperm_f(srclane, v.y);
    const float gz = bperm_f(srclane, v.z), gw = bperm_f(srclane, v.w);
    const float lo = (csel & 1) ? gy : gx;
    const float hi = (csel & 1) ? gw : gz;
    return (csel & 2) ? hi : lo;
}
// double butterfly-xor shuffle (two 32-bit halves)
__device__ __forceinline__ double shflx_d(double v, int mask) {
    const long long x = __double_as_longlong(v);
    int lo = (int)(x & 0xffffffffLL), hi = (int)(x >> 32);
    lo = __shfl_xor(lo, mask, 64);
    hi = __shfl_xor(hi, mask, 64);
    return __longlong_as_double(((long long)hi << 32) | (unsigned)(unsigned int)lo);
}

__device__ __forceinline__ void unpack8(uint4 raw, float (&dv)[8]) {
    const __half2 h0 = *reinterpret_cast<const __half2*>(&raw.x);
    const __half2 h1 = *reinterpret_cast<const __half2*>(&raw.y);
    const __half2 h2 = *reinterpret_cast<const __half2*>(&raw.z);
    const __half2 h3 = *reinterpret_cast<const __half2*>(&raw.w);
    dv[0] = __low2float(h0); dv[1] = __high2float(h0);
    dv[2] = __low2float(h1); dv[3] = __high2float(h1);
    dv[4] = __low2float(h2); dv[5] = __high2float(h2);
    dv[6] = __low2float(h3); dv[7] = __high2float(h3);
}

// ---- forward: 8 steps + CONDITIONAL renorm ----
template<bool GUARD>
__device__ __forceinline__ void do_chunk(uint4 raw, int t0, int inlen, float skf,
                                         float& aO, float& aE, float& r0, float& Rtot)
{
    float dv[8]; unpack8(raw, dv);
    float sd[8];
#pragma unroll
    for (int j = 0; j < 8; ++j) sd[j] = skf * dv[j];
#pragma unroll
    for (int j = 0; j < 8; ++j) {
        if (!GUARD || (t0 + j < inlen)) {
            const float ad = aO * dv[j];
            const float pE = wshr1(aE, r0);
            const float pO = wshr1(aO, 0.0f);
            const float nO = fmaf(pE, dv[j], fmaf(pO, sd[j], ad));
            aE += aO;
            aO = nO;
        }
    }
    const float mx = fmaxf(fmaxf(aO, aE), r0);
    if (__any(mx >= RENORM_THR)) {
        const float M_ = xmax64(mx);
        int R_ = (int)(__float_as_uint(M_) >> 23) - 127;
        R_ = (R_ < 0) ? 0 : ((R_ > 126) ? 126 : R_);
        const float sc = __uint_as_float((unsigned)(127 - R_) << 23);
        aO = fminf(aO * sc, 4.0f);
        aE = fminf(aE * sc, 4.0f);
        r0 = fminf(r0 * sc, 4.0f);
        Rtot += (float)R_;
    }
}

// ---- backward (transpose), j descending, CONDITIONAL renorm ----
// bO_l' = w_l*bO_l + bE_l + skf_{l+1}*(w*bO)_{l+1};  bE_l' = bE_l + (w*bO)_{l+1}
// br0'  = br0 + w_0*bO_0  (lane0-valid; other lanes garbage, excluded from
//                          the trigger/max, scaled alongside -> bounded)
template<bool GUARD>
__device__ __forceinline__ void do_chunk_bwd(uint4 raw, int t0, int inlen, float skfb,
                                             float& bO, float& bE, float& br, float& Rb,
                                             int l)
{
    float dv[8]; unpack8(raw, dv);
#pragma unroll
    for (int j = 7; j >= 0; --j) {
        if (!GUARD || (t0 + j < inlen)) {
            const float BOw = bO * dv[j];
            const float uO  = wshl1(BOw, 0.0f);
            const float t1  = bE + BOw;
            bE += uO;
            br += BOw;
            bO  = fmaf(skfb, uO, t1);
        }
    }
    const float brm = (l == 0) ? br : 0.0f;
    const float mx = fmaxf(fmaxf(bO, bE), brm);
    if (__any(mx >= RENORM_THR)) {
        const float M_ = xmax64(mx);
        int R_ = (int)(__float_as_uint(M_) >> 23) - 127;
        R_ = (R_ < 0) ? 0 : ((R_ > 126) ? 126 : R_);
        const float sc = __uint_as_float((unsigned)(127 - R_) << 23);
        bO = bO * sc;
        bE = bE * sc;
        br = br * sc;
        Rb += (float)R_;
    }
}

__global__ __launch_bounds__(1024, 1) void ctc_fused8_kernel(
    const int* __restrict__ y_true,      // [B, 64]
    const float* __restrict__ y_pred,    // [B, T, C]
    const int* __restrict__ in_len,      // [B]
    const int* __restrict__ lab_len,     // [B]
    float* __restrict__ out)             // [B]
{
    __shared__ __half w_lds[Tt / 8][64][8];   // [chunk][lane][t&7], 64 KB
    __shared__ float  ps[2 * NPS];            // per-producer blank partials (log2)
    __shared__ int    fctr[5], bctr[5];       // per-round counters (asc / desc)
    __shared__ int    bdone, pdone;
    __shared__ float  bstate[130];            // bE[64], bO[64], br0, Rb

    const int b   = blockIdx.x;
    const int tid = threadIdx.x;
    const int w   = tid >> 6;            // wave 0..15
    const int l   = tid & 63;

    if (tid < 5) { fctr[tid] = 0; bctr[tid] = 0; }
    if (tid == 0) { bdone = 0; pdone = 0; }
    __syncthreads();

    int inlen = in_len[b]; if (inlen < 1) inlen = 1; if (inlen > Tt) inlen = Tt;
    int LLv   = lab_len[b]; if (LLv < 1) LLv = 1; if (LLv > Ll) LLv = Ll;

    const int nct  = (inlen + 7) >> 3;   // total chunks (>= 32)
    const int nchf = nct >> 1;           // forward chunks [0, nchf)
    const int nchb = nct - nchf;         // backward chunks [nchf, nct), top-down

    const int lab = y_true[b * Ll + l] & 127;
    const float* rowbase = y_pred + (size_t)b * Tt * Cc;

    if (w >= 2) {
        // ---------------- producers: 7 ascending (w=2..8), 7 descending ---------
        const bool asc = (w < 9);
        const int pw    = asc ? (w - 2) : (w - 9);
        const int nside = asc ? nchf : nchb;
        const int half = l >> 5, li = l & 31;
        const int srcA = lab >> 2;
        const int csel = lab & 3;
        const bool live = (l < LLv);
        int* ctr = asc ? fctr : bctr;

        float acc = 0.0f;

        if (pw < nside) {
            const int c0 = asc ? pw : (nct - 1 - pw);
            float4 vb[4];
#pragma unroll
            for (int j = 0; j < 4; ++j)
                vb[j] = ((const float4*)(rowbase + (size_t)(c0 * 8 + 2 * j + half) * Cc))[li];

            for (int k = pw, idx = 0; k < nside; k += NPS, ++idx) {
                const int c  = asc ? k : (nct - 1 - k);
                const int kn = k + NPS;
                const int cn = (kn < nside) ? (asc ? kn : (nct - 1 - kn)) : 0;  // clamp: legal dummy
                float prod = 1.0f, bsum = 0.0f;
#pragma unroll
                for (int j = 0; j < 4; ++j) {
                    const float4 v = vb[j];
                    vb[j] = ((const float4*)(rowbase + (size_t)(cn * 8 + 2 * j + half) * Cc))[li];

                    const int rA = c * 8 + 2 * j;
                    const int rB = rA + 1;

                    float e = (fexp2(v.x * INV_LN2) + fexp2(v.y * INV_LN2))
                            + (fexp2(v.z * INV_LN2) + fexp2(v.w * INV_LN2));
                    e = rowsum(e);
                    // broadcasts via bpermute (VGPR-only; no SALU hazards)
                    const float sA = sflf(e, 15) + sflf(e, 31);
                    const float sB = sflf(e, 47) + sflf(e, 63);
                    const float blA = sflf(v.w, 31);
                    const float blB = sflf(v.w, 63);

                    const bool okA = rA < inlen, okB = rB < inlen;
                    prod *= okB ? sA * sB : (okA ? sA : 1.0f);
                    bsum += okB ? blA + blB : (okA ? blA : 0.0f);

                    const float xA = gather4(v, srcA, csel);
                    const float xB = gather4(v, srcA + 32, csel);
                    float wA = fminf(fmaxf(fexp2((xA - blA) * INV_LN2), 6.1e-5f), 8192.0f);
                    float wB = fminf(fmaxf(fexp2((xB - blB) * INV_LN2), 6.1e-5f), 8192.0f);
                    wA = live ? wA : 0.0f;
                    wB = live ? wB : 0.0f;
                    const unsigned packed =
                          (unsigned)__half_as_ushort(__float2half(wA))
                        | ((unsigned)__half_as_ushort(__float2half(wB)) << 16);
                    *(unsigned*)&w_lds[c][l][2 * j] = packed;
                }
                acc = fmaf(bsum, INV_LN2, acc) - flog2(prod);
                asm volatile("s_waitcnt lgkmcnt(0)" ::: "memory");
                if (l == 0) atomicAdd(&ctr[idx], 1);
            }
        }
        if (l == 0) ps[(asc ? 0 : NPS) + pw] = acc;
        asm volatile("s_waitcnt lgkmcnt(0)" ::: "memory");
        if (l == 0) atomicAdd(&pdone, 1);
        return;
    }

    // common to both consumers
    const int labp = __shfl_up(lab, 1, 64);
    const float skf = ((l >= 1) && (lab != labp)) ? 1.0f : 0.0f;

    if (w == 1) {
        // ---------------- backward consumer: beta recurrence, top-down ----------
        const float skfb = __shfl(skf, (l + 1) & 63, 64); // lane63: uO=0, value unused
        float bE = (l == LLv - 1) ? 1.0f : 0.0f;     // state 2*LLv (final blank)
        float bO = bE;                               // state 2*LLv-1 (final label)
        float br = 0.0f, Rb = 0.0f;

        volatile int* vd = bctr;
        int readyd = 0, rrd = 0;
        auto wait_d = [&](int cb) {                  // chunk cb ready (top-down count)
            const int needcnt = nct - cb;
            while (readyd < needcnt) {
                const int rem  = nchb - rrd * NPS;
                const int need = rem < NPS ? rem : NPS;
                if (vd[rrd] >= need) { readyd += need; ++rrd; }
                else __builtin_amdgcn_s_sleep(1);
            }
            asm volatile("" ::: "memory");
        };

        if (nchb > 0) {
            wait_d(nct - 1);
            uint4 A = *(const uint4*)&w_lds[nct - 1][l][0];
            for (int cb = nct - 1; cb >= nchf; --cb) {
                uint4 Bv = A;
                if (cb - 1 >= nchf) { wait_d(cb - 1); Bv = *(const uint4*)&w_lds[cb - 1][l][0]; }
                const int t0 = cb * 8;
                if (t0 + 8 <= inlen) do_chunk_bwd<false>(A, t0, inlen, skfb, bO, bE, br, Rb, l);
                else                 do_chunk_bwd<true >(A, t0, inlen, skfb, bO, bE, br, Rb, l);
                A = Bv;
            }
        }
        bstate[l]      = bE;
        bstate[64 + l] = bO;
        if (l == 0) { bstate[128] = br; bstate[129] = Rb; }
        asm volatile("s_waitcnt lgkmcnt(0)" ::: "memory");
        if (l == 0) atomicExch(&bdone, 1);
        return;
    }

    // ---------------- forward consumer: alpha recurrence, chunks [0,nchf) -------
    float aO = 0.0f, aE = 0.0f, r0 = 1.0f, Rf = 0.0f;

    volatile int* vf = fctr;
    int readyf = 0, rrf = 0;
    auto wait_f = [&](int cneed) {
        while (readyf <= cneed) {
            const int rem  = nchf - rrf * NPS;
            const int need = rem < NPS ? rem : NPS;
            if (vf[rrf] >= need) { readyf += need; ++rrf; }
            else __builtin_amdgcn_s_sleep(1);
        }
        asm volatile("" ::: "memory");
    };

    if (nchf > 0) {
        wait_f(0);
        uint4 A = *(const uint4*)&w_lds[0][l][0];
        for (int c = 0; c < nchf; ++c) {
            uint4 Bv = A;
            if (c + 1 < nchf) { wait_f(c + 1); Bv = *(const uint4*)&w_lds[c + 1][l][0]; }
            const int t0 = c * 8;
            if (t0 + 8 <= inlen) do_chunk<false>(A, t0, inlen, skf, aO, aE, r0, Rf);
            else                 do_chunk<true >(A, t0, inlen, skf, aO, aE, r0, Rf);
            A = Bv;
        }
    }

    // wait: all producers published ps; backward published bstate
    {
        volatile int* vp = &pdone;
        while (*vp < 2 * NPS) __builtin_amdgcn_s_sleep(1);
        volatile int* vbd = &bdone;
        while (*vbd == 0) __builtin_amdgcn_s_sleep(1);
        asm volatile("" ::: "memory");
    }

    float cum_b = 0.0f;
#pragma unroll
    for (int q = 0; q < 2 * NPS; ++q) cum_b += ps[q];

    // meeting-point dot in DOUBLE (exponent-safe): s = sum_s alpha(s)*beta(s)
    const float bEl = bstate[l], bOl = bstate[64 + l];
    const float br0 = bstate[128], Rb = bstate[129];
    double cd = (double)aE * (double)bEl + (double)aO * (double)bOl;
    if (l == 0) cd += (double)r0 * (double)br0;
#pragma unroll
    for (int mk = 1; mk < 64; mk <<= 1) cd += shflx_d(cd, mk);
    // log2 of the double via exponent extraction (cd uniform across lanes now)
    double sd_ = cd > 1e-300 ? cd : 1e-300;
    const long long u = __double_as_longlong(sd_);
    const int e2 = (int)((u >> 52) & 0x7ff) - 1023;
    const double mant = __longlong_as_double((u & 0xfffffffffffffLL) | 0x3ff0000000000000LL);
    const float l2s = (float)e2 + flog2((float)mant);
    if (l == 0)
        out[b] = -LN2_F * (l2s + Rf + Rb + cum_b);
}

extern "C" void kernel_launch(void* const* d_in, const int* in_sizes, int n_in,
                              void* d_out, int out_size, void* d_ws, size_t ws_size,
                              hipStream_t stream) {
    const int*   y_true  = (const int*)d_in[0];    // [256,64]
    const float* y_pred  = (const float*)d_in[1];  // [256,512,128]
    const int*   in_len  = (const int*)d_in[2];    // [256]
    const int*   lab_len = (const int*)d_in[3];    // [256]
    float*       out     = (float*)d_out;          // [256]
    (void)d_ws; (void)ws_size;

    ctc_fused8_kernel<<<256, 1024, 0, stream>>>(y_true, y_pred, in_len, lab_len, out);
}

// Round 7
// 108.617 us; speedup vs baseline: 1.0647x; 1.0033x over previous
//
#include <hip/hip_runtime.h>
#include <hip/hip_fp16.h>
#include <math.h>

// CTC loss forward, SINGLE fused kernel v9: fwd-bwd split consumers (v8) +
// LDS-PIPE-STARVED producers.
// One block of 1024 threads (16 waves) per batch element; B=256 = 256 CUs.
//
// Model refit (v7/v8 nulls): chain cost is ~6.5us (v2->v3 delta measured it
// directly); prep is ~32us vs 10.4us HBM floor. The excess is the per-CU
// LDS pipe: old producers issued ~58 LDS-pipe ops/chunk (gather4 = 8
// bpermutes/row-pair, 6 shfl broadcasts, 4 ds_write_b32) x 64 chunks with
// 14 waves contending on ONE pipe ~= 15-25us serialization. (v8's
// readlane->shfl change made it worse; OccupancyPercent that drove the old
// "chain-bound" model is a gfx94x-formula fallback, unverified on gfx950.)
// v9 producers: one wave owns a whole chunk (8 rows, float2 layout: classes
// 2l,2l+1): label gather = 2 bpermutes/row (fixed index lab>>1); row sums
// via readlane+VALU (SALU/VALU pipes, hazards hidden by 14-wave TLP);
// blank = readlane(v.y,63); 8 rows pack to uint4 -> ONE ds_write_b128 per
// chunk. LDS-pipe ops/chunk: 58 -> 17. Consumers = v8 verbatim
// (cond renorm, f64 combiner). B=256, T=512, C=128 (blank=127), L=64.

constexpr int Cc = 128;
constexpr int Tt = 512;
constexpr int Ll = 64;
constexpr int NPS = 7;                      // producer waves per side
constexpr float INV_LN2 = 1.4426950408889634f;
constexpr float LN2_F   = 0.6931471805599453f;
constexpr float RENORM_THR = 16777216.0f;   // 2^24

__device__ __forceinline__ float fexp2(float x) { return __builtin_amdgcn_exp2f(x); }
__device__ __forceinline__ float flog2(float x) { return __builtin_amdgcn_logf(x); }

template<int CTRL, bool BC>
__device__ __forceinline__ float dppf(float old, float x) {
    return __int_as_float(__builtin_amdgcn_update_dpp(
        __float_as_int(old), __float_as_int(x), CTRL, 0xF, 0xF, BC));
}
// lane i <- lane i-1; lane 0 <- fill. (silicon-proven r3-r7)
__device__ __forceinline__ float wshr1(float x, float fill) { return dppf<0x138, false>(fill, x); }
// lane i <- lane i+1; lane 63 <- fill. (wave_shl1, mirror, proven v7)
__device__ __forceinline__ float wshl1(float x, float fill) { return dppf<0x130, false>(fill, x); }

__device__ __forceinline__ float rlf(float v, int lane) {
    return __int_as_float(__builtin_amdgcn_readlane(__float_as_int(v), lane));
}
// Row-local (16-lane) reduce; lanes 15/31/47/63 hold row results. (proven r6/r7)
__device__ __forceinline__ float rowsum(float e) {
    e += dppf<0x111, true>(0.f, e);
    e += dppf<0x112, true>(0.f, e);
    e += dppf<0x114, true>(0.f, e);
    e += dppf<0x118, true>(0.f, e);
    return e;
}
// all-lane wave max via butterfly shuffles (VGPR-only; used in rare renorm)
__device__ __forceinline__ float xmax64(float m) {
    m = fmaxf(m, __shfl_xor(m, 32, 64));
    m = fmaxf(m, __shfl_xor(m, 16, 64));
    m = fmaxf(m, __shfl_xor(m,  8, 64));
    m = fmaxf(m, __shfl_xor(m,  4, 64));
    m = fmaxf(m, __shfl_xor(m,  2, 64));
    m = fmaxf(m, __shfl_xor(m,  1, 64));
    return m;
}
__device__ __forceinline__ float bperm_f(int srclane, float v) {
    return __int_as_float(__builtin_amdgcn_ds_bpermute(srclane << 2, __float_as_int(v)));
}
// double butterfly-xor shuffle (two 32-bit halves)
__device__ __forceinline__ double shflx_d(double v, int mask) {
    const long long x = __double_as_longlong(v);
    int lo = (int)(x & 0xffffffffLL), hi = (int)(x >> 32);
    lo = __shfl_xor(lo, mask, 64);
    hi = __shfl_xor(hi, mask, 64);
    return __longlong_as_double(((long long)hi << 32) | (unsigned)(unsigned int)lo);
}

__device__ __forceinline__ void unpack8(uint4 raw, float (&dv)[8]) {
    const __half2 h0 = *reinterpret_cast<const __half2*>(&raw.x);
    const __half2 h1 = *reinterpret_cast<const __half2*>(&raw.y);
    const __half2 h2 = *reinterpret_cast<const __half2*>(&raw.z);
    const __half2 h3 = *reinterpret_cast<const __half2*>(&raw.w);
    dv[0] = __low2float(h0); dv[1] = __high2float(h0);
    dv[2] = __low2float(h1); dv[3] = __high2float(h1);
    dv[4] = __low2float(h2); dv[5] = __high2float(h2);
    dv[6] = __low2float(h3); dv[7] = __high2float(h3);
}

// ---- forward: 8 steps + CONDITIONAL renorm (v8-proven) ----
template<bool GUARD>
__device__ __forceinline__ void do_chunk(uint4 raw, int t0, int inlen, float skf,
                                         float& aO, float& aE, float& r0, float& Rtot)
{
    float dv[8]; unpack8(raw, dv);
    float sd[8];
#pragma unroll
    for (int j = 0; j < 8; ++j) sd[j] = skf * dv[j];
#pragma unroll
    for (int j = 0; j < 8; ++j) {
        if (!GUARD || (t0 + j < inlen)) {
            const float ad = aO * dv[j];
            const float pE = wshr1(aE, r0);
            const float pO = wshr1(aO, 0.0f);
            const float nO = fmaf(pE, dv[j], fmaf(pO, sd[j], ad));
            aE += aO;
            aO = nO;
        }
    }
    const float mx = fmaxf(fmaxf(aO, aE), r0);
    if (__any(mx >= RENORM_THR)) {
        const float M_ = xmax64(mx);
        int R_ = (int)(__float_as_uint(M_) >> 23) - 127;
        R_ = (R_ < 0) ? 0 : ((R_ > 126) ? 126 : R_);
        const float sc = __uint_as_float((unsigned)(127 - R_) << 23);
        aO = fminf(aO * sc, 4.0f);
        aE = fminf(aE * sc, 4.0f);
        r0 = fminf(r0 * sc, 4.0f);
        Rtot += (float)R_;
    }
}

// ---- backward (transpose), j descending, CONDITIONAL renorm (v8-proven) ----
template<bool GUARD>
__device__ __forceinline__ void do_chunk_bwd(uint4 raw, int t0, int inlen, float skfb,
                                             float& bO, float& bE, float& br, float& Rb,
                                             int l)
{
    float dv[8]; unpack8(raw, dv);
#pragma unroll
    for (int j = 7; j >= 0; --j) {
        if (!GUARD || (t0 + j < inlen)) {
            const float BOw = bO * dv[j];
            const float uO  = wshl1(BOw, 0.0f);
            const float t1  = bE + BOw;
            bE += uO;
            br += BOw;
            bO  = fmaf(skfb, uO, t1);
        }
    }
    const float brm = (l == 0) ? br : 0.0f;
    const float mx = fmaxf(fmaxf(bO, bE), brm);
    if (__any(mx >= RENORM_THR)) {
        const float M_ = xmax64(mx);
        int R_ = (int)(__float_as_uint(M_) >> 23) - 127;
        R_ = (R_ < 0) ? 0 : ((R_ > 126) ? 126 : R_);
        const float sc = __uint_as_float((unsigned)(127 - R_) << 23);
        bO = bO * sc;
        bE = bE * sc;
        br = br * sc;
        Rb += (float)R_;
    }
}

__global__ __launch_bounds__(1024, 1) void ctc_fused9_kernel(
    const int* __restrict__ y_true,      // [B, 64]
    const float* __restrict__ y_pred,    // [B, T, C]
    const int* __restrict__ in_len,      // [B]
    const int* __restrict__ lab_len,     // [B]
    float* __restrict__ out)             // [B]
{
    __shared__ __half w_lds[Tt / 8][64][8];   // [chunk][lane][t&7], 64 KB
    __shared__ float  ps[2 * NPS];            // per-producer blank partials (log2)
    __shared__ int    fctr[10], bctr[10];     // per-round counters (asc / desc)
    __shared__ int    bdone, pdone;
    __shared__ float  bstate[130];            // bE[64], bO[64], br0, Rb

    const int b   = blockIdx.x;
    const int tid = threadIdx.x;
    const int w   = tid >> 6;            // wave 0..15
    const int l   = tid & 63;

    if (tid < 10) { fctr[tid] = 0; bctr[tid] = 0; }
    if (tid == 0) { bdone = 0; pdone = 0; }
    __syncthreads();

    int inlen = in_len[b]; if (inlen < 1) inlen = 1; if (inlen > Tt) inlen = Tt;
    int LLv   = lab_len[b]; if (LLv < 1) LLv = 1; if (LLv > Ll) LLv = Ll;

    const int nct  = (inlen + 7) >> 3;   // total chunks (>= 32)
    const int nchf = nct >> 1;           // forward chunks [0, nchf)
    const int nchb = nct - nchf;         // backward chunks [nchf, nct), top-down

    const int lab = y_true[b * Ll + l] & 127;
    const float* rowbase = y_pred + (size_t)b * Tt * Cc;

    if (w >= 2) {
        // ------------- producers: one wave owns a whole chunk (8 rows) ----------
        // float2 layout: lane l holds classes 2l, 2l+1 of each row.
        const bool asc = (w < 9);
        const int pw    = asc ? (w - 2) : (w - 9);
        const int nside = asc ? nchf : nchb;
        const int glane = lab >> 1;          // fixed bpermute source lane
        const int lsel  = lab & 1;           // .x or .y at that lane
        const bool live = (l < LLv);         // dead lattice lanes -> w = 0
        int* ctr = asc ? fctr : bctr;

        float acc = 0.0f;

        for (int k = pw, idx = 0; k < nside; k += NPS, ++idx) {
            const int c = asc ? k : (nct - 1 - k);
            const int row0 = c * 8;
            // load the whole chunk coalesced (8 x 512B), MLP = 8
            float2 rv[8];
#pragma unroll
            for (int t = 0; t < 8; ++t)
                rv[t] = ((const float2*)(rowbase + (size_t)(row0 + t) * Cc))[l];

            float prod = 1.0f, bsum = 0.0f;
            uint4 pk;

            // per-row worker: returns packed half bits of w for row row0+t.
            auto wbits = [&](int t) -> unsigned {
                const float2 v = rv[t];
                float e = fexp2(v.x * INV_LN2) + fexp2(v.y * INV_LN2);
                e = rowsum(e);
                // 64-lane sum + blank via readlane (SALU/VALU pipes; TLP hides
                // hazards at 4 waves/SIMD — the LDS pipe is the scarce one)
                const float s  = (rlf(e, 15) + rlf(e, 31)) + (rlf(e, 47) + rlf(e, 63));
                const float bl = rlf(v.y, 63);         // class 127 logit
                const bool ok = (row0 + t) < inlen;
                prod *= ok ? s : 1.0f;
                bsum += ok ? bl : 0.0f;
                // label gather: 2 bpermutes with FIXED index (was 8)
                const float xa = bperm_f(glane, v.x);
                const float xb = bperm_f(glane, v.y);
                const float xl = lsel ? xb : xa;
                float ww = fminf(fmaxf(fexp2((xl - bl) * INV_LN2), 6.1e-5f), 8192.0f);
                ww = live ? ww : 0.0f;
                return (unsigned)__half_as_ushort(__float2half(ww));
            };
            pk.x = wbits(0) | (wbits(1) << 16);
            pk.y = wbits(2) | (wbits(3) << 16);
            pk.z = wbits(4) | (wbits(5) << 16);
            pk.w = wbits(6) | (wbits(7) << 16);

            acc = fmaf(bsum, INV_LN2, acc) - flog2(prod);
            *(uint4*)&w_lds[c][l][0] = pk;             // ONE ds_write_b128/chunk
            asm volatile("s_waitcnt lgkmcnt(0)" ::: "memory");
            if (l == 0) atomicAdd(&ctr[idx], 1);
        }
        if (l == 0) ps[(asc ? 0 : NPS) + pw] = acc;
        asm volatile("s_waitcnt lgkmcnt(0)" ::: "memory");
        if (l == 0) atomicAdd(&pdone, 1);
        return;
    }

    // common to both consumers
    const int labp = __shfl_up(lab, 1, 64);
    const float skf = ((l >= 1) && (lab != labp)) ? 1.0f : 0.0f;

    if (w == 1) {
        // ---------------- backward consumer: beta recurrence, top-down ----------
        const float skfb = __shfl(skf, (l + 1) & 63, 64); // lane63: uO=0, value unused
        float bE = (l == LLv - 1) ? 1.0f : 0.0f;     // state 2*LLv (final blank)
        float bO = bE;                               // state 2*LLv-1 (final label)
        float br = 0.0f, Rb = 0.0f;

        volatile int* vd = bctr;
        int readyd = 0, rrd = 0;
        auto wait_d = [&](int cb) {                  // chunk cb ready (top-down count)
            const int needcnt = nct - cb;
            while (readyd < needcnt) {
                const int rem  = nchb - rrd * NPS;
                const int need = rem < NPS ? rem : NPS;
                if (vd[rrd] >= need) { readyd += need; ++rrd; }
                else __builtin_amdgcn_s_sleep(1);
            }
            asm volatile("" ::: "memory");
        };

        if (nchb > 0) {
            wait_d(nct - 1);
            uint4 A = *(const uint4*)&w_lds[nct - 1][l][0];
            for (int cb = nct - 1; cb >= nchf; --cb) {
                uint4 Bv = A;
                if (cb - 1 >= nchf) { wait_d(cb - 1); Bv = *(const uint4*)&w_lds[cb - 1][l][0]; }
                const int t0 = cb * 8;
                if (t0 + 8 <= inlen) do_chunk_bwd<false>(A, t0, inlen, skfb, bO, bE, br, Rb, l);
                else                 do_chunk_bwd<true >(A, t0, inlen, skfb, bO, bE, br, Rb, l);
                A = Bv;
            }
        }
        bstate[l]      = bE;
        bstate[64 + l] = bO;
        if (l == 0) { bstate[128] = br; bstate[129] = Rb; }
        asm volatile("s_waitcnt lgkmcnt(0)" ::: "memory");
        if (l == 0) atomicExch(&bdone, 1);
        return;
    }

    // ---------------- forward consumer: alpha recurrence, chunks [0,nchf) -------
    float aO = 0.0f, aE = 0.0f, r0 = 1.0f, Rf = 0.0f;

    volatile int* vf = fctr;
    int readyf = 0, rrf = 0;
    auto wait_f = [&](int cneed) {
        while (readyf <= cneed) {
            const int rem  = nchf - rrf * NPS;
            const int need = rem < NPS ? rem : NPS;
            if (vf[rrf] >= need) { readyf += need; ++rrf; }
            else __builtin_amdgcn_s_sleep(1);
        }
        asm volatile("" ::: "memory");
    };

    if (nchf > 0) {
        wait_f(0);
        uint4 A = *(const uint4*)&w_lds[0][l][0];
        for (int c = 0; c < nchf; ++c) {
            uint4 Bv = A;
            if (c + 1 < nchf) { wait_f(c + 1); Bv = *(const uint4*)&w_lds[c + 1][l][0]; }
            const int t0 = c * 8;
            if (t0 + 8 <= inlen) do_chunk<false>(A, t0, inlen, skf, aO, aE, r0, Rf);
            else                 do_chunk<true >(A, t0, inlen, skf, aO, aE, r0, Rf);
            A = Bv;
        }
    }

    // wait: all producers published ps; backward published bstate
    {
        volatile int* vp = &pdone;
        while (*vp < 2 * NPS) __builtin_amdgcn_s_sleep(1);
        volatile int* vbd = &bdone;
        while (*vbd == 0) __builtin_amdgcn_s_sleep(1);
        asm volatile("" ::: "memory");
    }

    float cum_b = 0.0f;
#pragma unroll
    for (int q = 0; q < 2 * NPS; ++q) cum_b += ps[q];

    // meeting-point dot in DOUBLE (exponent-safe): s = sum_s alpha(s)*beta(s)
    const float bEl = bstate[l], bOl = bstate[64 + l];
    const float br0 = bstate[128], Rb = bstate[129];
    double cd = (double)aE * (double)bEl + (double)aO * (double)bOl;
    if (l == 0) cd += (double)r0 * (double)br0;
#pragma unroll
    for (int mk = 1; mk < 64; mk <<= 1) cd += shflx_d(cd, mk);
    // log2 of the double via exponent extraction (cd uniform across lanes now)
    double sd_ = cd > 1e-300 ? cd : 1e-300;
    const long long u = __double_as_longlong(sd_);
    const int e2 = (int)((u >> 52) & 0x7ff) - 1023;
    const double mant = __longlong_as_double((u & 0xfffffffffffffLL) | 0x3ff0000000000000LL);
    const float l2s = (float)e2 + flog2((float)mant);
    if (l == 0)
        out[b] = -LN2_F * (l2s + Rf + Rb + cum_b);
}

extern "C" void kernel_launch(void* const* d_in, const int* in_sizes, int n_in,
                              void* d_out, int out_size, void* d_ws, size_t ws_size,
                              hipStream_t stream) {
    const int*   y_true  = (const int*)d_in[0];    // [256,64]
    const float* y_pred  = (const float*)d_in[1];  // [256,512,128]
    const int*   in_len  = (const int*)d_in[2];    // [256]
    const int*   lab_len = (const int*)d_in[3];    // [256]
    float*       out     = (float*)d_out;          // [256]
    (void)d_ws; (void)ws_size;

    ctc_fused9_kernel<<<256, 1024, 0, stream>>>(y_true, y_pred, in_len, lab_len, out);
}